// Round 11
// baseline (590.429 us; speedup 1.0000x reference)
//
#include <hip/hip_runtime.h>
#include <math.h>
#include <type_traits>

// Problem constants (match reference file)
#define N_NODES_C 100000
#define DIM_C     128
#define DMSG_C    512
#define N_EDGES_C 200000

// GEMM geometry: 128 nodes/block (8 node-groups of 16), 512 gate rows = 32 tiles
#define GROUPS_PAD 6256            // 782 gemm blocks * 8 groups
#define NODES_PAD  (GROUPS_PAD*16) // 100096

typedef __attribute__((ext_vector_type(8))) __bf16 bf16x8;
typedef __attribute__((ext_vector_type(4))) float  f32x4;

__device__ __forceinline__ float sigmoidf_(float x) { return 1.0f / (1.0f + __expf(-x)); }
// fast tanh: 1 - 2/(e^{2x}+1); exact at +/-inf, ~1e-7 abs err mid-range
__device__ __forceinline__ float tanhf_(float x) { return 1.0f - 2.0f / (__expf(2.0f * x) + 1.0f); }
__device__ __forceinline__ unsigned short f2bf(float x) {
    union { float f; unsigned u; } v; v.f = x;
    unsigned r = v.u + 0x7FFFu + ((v.u >> 16) & 1u);   // RNE
    return (unsigned short)(r >> 16);
}
__device__ __forceinline__ float bf2f(unsigned short b) {
    union { float f; unsigned u; } v; v.u = ((unsigned)b) << 16; return v.f;
}
__device__ __forceinline__ void st8(void* p, float4 lo, float4 hi) {
    union { bf16x8 v; unsigned short u[8]; } r;
    r.u[0] = f2bf(lo.x); r.u[1] = f2bf(lo.y); r.u[2] = f2bf(lo.z); r.u[3] = f2bf(lo.w);
    r.u[4] = f2bf(hi.x); r.u[5] = f2bf(hi.y); r.u[6] = f2bf(hi.z); r.u[7] = f2bf(hi.w);
    *(bf16x8*)p = r.v;
}

// ---- last occurrence of each node in edge order ----
__global__ void scatter_last_kernel(const int* __restrict__ src, const int* __restrict__ dst,
                                    int* __restrict__ idx_s, int* __restrict__ idx_d) {
    int e = blockIdx.x * blockDim.x + threadIdx.x;
    if (e < N_EDGES_C) {
        atomicMax(&idx_s[src[e]], e);
        atomicMax(&idx_d[dst[e]], e);
    }
}

// =====================  MAIN (split) PATH  =====================
// Wsw[tile][kk][lane][8]: B-fragment order. tile T holds packed gate rows T*16+(l&15):
//   tiles 0-7 r, 8-15 z, 16-23 i_n (W_ih), 24-31 h_n (W_hh rows 256..383)
// K map: 0..127 self, 128..255 other, 256..383 ef, 384..511 enc, 512..639 h
__global__ void build_wallsw_kernel(const float* __restrict__ W_ih, const float* __restrict__ W_hh,
                                    unsigned short* __restrict__ Wsw) {
    int id = blockIdx.x * 256 + threadIdx.x;           // 32*20*64 = 40960
    if (id >= 32 * 20 * 64) return;
    int tile = id / 1280, r = id - tile * 1280, kk = r >> 6, l = r & 63;
    int pr = tile * 16 + (l & 15);
    int k0 = kk * 32 + ((l >> 4) & 3) * 8;
    float v[8];
#pragma unroll
    for (int j = 0; j < 8; ++j) {
        int k = k0 + j;
        if (pr < 256)      v[j] = (k < 512) ? W_ih[(long)pr * DMSG_C + k] : W_hh[(long)pr * DIM_C + (k - 512)];
        else if (pr < 384) v[j] = (k < 512) ? W_ih[(long)pr * DMSG_C + k] : 0.0f;
        else               v[j] = (k >= 512) ? W_hh[(long)(pr - 128) * DIM_C + (k - 512)] : 0.0f;
    }
    union { bf16x8 bv; unsigned short u[8]; } o;
#pragma unroll
    for (int j = 0; j < 8; ++j) o.u[j] = f2bf(v[j]);
    *(bf16x8*)((char*)Wsw + ((size_t)(tile * 20 + kk) << 10) + ((size_t)l << 4)) = o.bv;
}

// Gather: 16 nodes/block. Builds Xs (12 chunks: self|otherS|efS) and Xd
// (8 chunks: otherD|efD) in A-frag-swizzled bf16, dt arrays, out_lu, and the
// inactive-pass0 copy of memory into out_mem.
__global__ __launch_bounds__(256) void gather_kernel(
    const float* __restrict__ memory, const float* __restrict__ last_update,
    const float* __restrict__ edge_times, const float* __restrict__ edge_feat,
    const int* __restrict__ src, const int* __restrict__ dst,
    const int* __restrict__ idx_s, const int* __restrict__ idx_d,
    float* __restrict__ dt_s, float* __restrict__ dt_d,
    unsigned short* __restrict__ Xs, unsigned short* __restrict__ Xd,
    float* __restrict__ out_mem, float* __restrict__ out_lu)
{
    __shared__ int es_l[16], ed_l[16], os_l[16], od_l[16];
    const int t = threadIdx.x;
    const int base = blockIdx.x * 16;
    if (t < 16) {
        const int n = base + t;
        const int es = idx_s[n], ed = idx_d[n];
        const int eus = es < 0 ? 0 : es, eud = ed < 0 ? 0 : ed;
        es_l[t] = es; ed_l[t] = ed;
        os_l[t] = dst[eus]; od_l[t] = src[eud];
        const float lun = last_update[n];
        const float ts = edge_times[eus], td = edge_times[eud];
        dt_s[n] = ts - lun; dt_d[n] = td - lun;
        out_lu[n] = (ed >= 0) ? td : ((es >= 0) ? ts : lun);
    }
    __syncthreads();
    const int m = t & 15, q = t >> 4;                  // node-in-block, col-chunk (8 cols)
    const int n = base + m;
    const size_t g = blockIdx.x;                       // node-group == block
    const int es = es_l[m];
    const int eus = (es < 0) ? 0 : es;
    const int eud = (ed_l[m] < 0) ? 0 : ed_l[m];
    const float4* self_p = (const float4*)(memory + (size_t)n * DIM_C + q * 8);
    const float4* oS_p   = (const float4*)(memory + (size_t)os_l[m] * DIM_C + q * 8);
    const float4* oD_p   = (const float4*)(memory + (size_t)od_l[m] * DIM_C + q * 8);
    const float4* eS_p   = (const float4*)(edge_feat + (size_t)eus * DIM_C + q * 8);
    const float4* eD_p   = (const float4*)(edge_feat + (size_t)eud * DIM_C + q * 8);
    float4 s0 = self_p[0], s1 = self_p[1];
    float4 a0 = oS_p[0],   a1 = oS_p[1];
    float4 b0 = oD_p[0],   b1 = oD_p[1];
    float4 c0 = eS_p[0],   c1 = eS_p[1];
    float4 d0 = eD_p[0],   d1 = eD_p[1];
    const int kkq = q >> 2;
    const size_t laneoff = (size_t)(((q & 3) * 16 + m)) << 4;
    char* XsB = (char*)Xs; char* XdB = (char*)Xd;
#define XOFFS(kk) ((((g * 12) + (kk)) << 10) + laneoff)
#define XOFFD(kk) ((((g * 8) + (kk)) << 10) + laneoff)
    st8(XsB + XOFFS(kkq),     s0, s1);
    st8(XsB + XOFFS(4 + kkq), a0, a1);
    st8(XsB + XOFFS(8 + kkq), c0, c1);
    st8(XdB + XOFFD(kkq),     b0, b1);
    st8(XdB + XOFFD(4 + kkq), d0, d1);
#undef XOFFS
#undef XOFFD
    if (es < 0) {   // inactive in pass0: seed out_mem with original memory row
        float4* op = (float4*)(out_mem + (size_t)n * DIM_C + q * 8);
        op[0] = s0; op[1] = s1;
    }
}

// R12 (resubmit): BOTH gemm passes fused in one kernel; h handed off via LDS
// (pass-1 block b depends only on pass-0 block b). No Hmir buffer (removes the
// 2-byte-store RMW + writeback + re-read that slowed R11's passes), no
// out_mem h re-read in pass 1, one fewer launch.
//
// 512 thr = 8 waves over 128 nodes (8 groups); wave w owns gate tiles
// {w, w+8, w+16, w+24}; acc[4 gate][8 group]; B wave-private 3 tiles/step.
// LDS 145 KB: RA 4-deep [sl4][g8][1KB] @0; B 2-deep [buf2][w8][si3][1KB]
// @32K; H [hc4][g8][1KB] @80K; ENC [ec4][g8][1KB] @112K; act flags @144K.
//
// P0: H region pre-filled from Xs self chunks 0-3 (read at st 0-3 AND the
//   H-phase st 12-15: h == original memory). RA stages Xs chunks 4-11.
//   Barriers: st0 (publish H) + st4..11 (publish RA). vmcnt: 3,4,5*7,4,3*9,0.
// Transition: barrier -> epilogue-0 (ds_read old h, gates, out_mem store,
//   ds_write h_new in place; each byte owned by one lane) -> P1 prologue DMA
//   (B0x3 + RA chunks 0-2) -> ENC recompute (dt_d) -> lgkm + barrier.
// P1: A = Xs self 0-3 / Xd 4-11 via RA (chunk st+3 staged at st<=8);
//   H st 12-15 straight from LDS. Barriers st0..11. vmcnt: 6,5*8,4,3*10,0
//   (st0's vmcnt(6) also retires the epilogue-0 stores, which are oldest).
// Epilogue-1: blend h from H-LDS (bf16), store out_mem for active-d nodes.
__global__ __launch_bounds__(512, 2) void gemm_fused_kernel(
    const unsigned short* __restrict__ Wsw,
    const float* __restrict__ b_ih, const float* __restrict__ b_hh,
    const unsigned short* __restrict__ Xs, const unsigned short* __restrict__ Xd,
    const float* __restrict__ dt_s, const float* __restrict__ dt_d,
    const int* __restrict__ idx_s, const int* __restrict__ idx_d,
    float* __restrict__ out_mem)
{
    __shared__ __align__(1024) char lds[148480];
    const int t = threadIdx.x;
    const int w = t >> 6, lane = t & 63, quad = lane >> 4, c = lane & 15;
    const long g0 = (long)blockIdx.x * 8;
    const long n0 = g0 * 16;
    const char* XsB = (const char*)Xs;
    const char* XdB = (const char*)Xd;
    const char* Wb  = (const char*)Wsw;
    const size_t laneoff = (size_t)lane << 4;

#define RAOF(sl, g)  ((((sl) * 8) + (g)) << 10)                       // 32 KB @0
#define BOFF(buf, si) (32768 + ((((buf) * 8 + w) * 3 + (si)) << 10))  // 48 KB @32K
#define HOFF(hc, g)  (81920 + ((((hc) * 8) + (g)) << 10))             // 32 KB @80K
#define EOFF(ec, g)  (114688 + ((((ec) * 8) + (g)) << 10))            // 32 KB @112K
    int* aS_l = (int*)(lds + 147456);   // [128]
    int* aD_l = (int*)(lds + 147968);   // [128]

    // ---- meta: activity flags (coalesced 4B loads) ----
    if (t < 128) {
        const long n = n0 + t;
        const bool valid = (n < N_NODES_C);
        const int nn = valid ? (int)n : 0;
        aS_l[t] = valid && (idx_s[nn] >= 0);
        aD_l[t] = valid && (idx_d[nn] >= 0);
    }

    // ---- dt for this wave's ENC share, both passes; retire before staging ----
    const int ecw = w & 3, gh = (w >> 2) * 4;
    float dtvS[4], dtvD[4];
#pragma unroll
    for (int g2 = 0; g2 < 4; ++g2) {
        dtvS[g2] = dt_s[(g0 + gh + g2) * 16 + c];
        dtvD[g2] = dt_d[(g0 + gh + g2) * 16 + c];
    }
    asm volatile("s_waitcnt vmcnt(0)" ::: "memory");
    __builtin_amdgcn_sched_barrier(0);

    auto stage = [&](const char* gsrc, int ldsoff) {
        __builtin_amdgcn_global_load_lds(
            (const __attribute__((address_space(1))) void*)(gsrc + laneoff),
            (__attribute__((address_space(3))) void*)(lds + ldsoff), 16, 0, 0);
    };
    auto b_src = [&](int k, int si) -> const char* {
        const bool hph = (k >= 12 && k < 16);
        const int tile = (si < 2) ? (w + 8 * si) : (hph ? (w + 24) : (w + 16));
        const int kk = (k < 12) ? k : (hph ? k + 4 : k - 4);
        return Wb + ((size_t)(tile * 20 + kk) << 10);
    };
    auto xs_src = [&](int k) -> const char* {   // Xs chunk k of group w
        return XsB + (((g0 + w) * 12 + k) << 10);
    };
    auto xd_src = [&](int k) -> const char* {   // Xd chunk k of group w
        return XdB + (((g0 + w) * 8 + k) << 10);
    };
    auto enc_fill = [&](const float* dtv) {     // wave fills chunk ecw, groups gh..gh+3
        const int f0 = ecw * 32 + quad * 8;
        float wf[8];
#pragma unroll
        for (int j = 0; j < 8; ++j) wf[j] = __expf(-0.16317532f * (float)(f0 + j));
#pragma unroll
        for (int g2 = 0; g2 < 4; ++g2) {
            union { bf16x8 v; unsigned short u[8]; } r;
#pragma unroll
            for (int j = 0; j < 8; ++j) r.u[j] = f2bf(__cosf(dtv[g2] * wf[j]));
            *(bf16x8*)(lds + EOFF(ecw, gh + g2) + laneoff) = r.v;
        }
    };

    f32x4 acc[4][8];
#pragma unroll
    for (int s = 0; s < 4; ++s)
#pragma unroll
        for (int g = 0; g < 8; ++g) acc[s][g] = (f32x4){0.f, 0.f, 0.f, 0.f};

#define MFMA_G(s, Bv, g) \
    acc[s][g] = __builtin_amdgcn_mfma_f32_16x16x32_bf16(A[g], Bv, acc[s][g], 0, 0, 0)
#define MFMA_ROW(s, Bv) \
    MFMA_G(s, Bv, 0); MFMA_G(s, Bv, 1); MFMA_G(s, Bv, 2); MFMA_G(s, Bv, 3); \
    MFMA_G(s, Bv, 4); MFMA_G(s, Bv, 5); MFMA_G(s, Bv, 6); MFMA_G(s, Bv, 7)

    auto run_pass = [&](auto PC) {
        constexpr int P = decltype(PC)::value;
#pragma unroll
        for (int st = 0; st < 20; ++st) {
            // stage B(st+1)
            if (st + 1 <= 19) {
#pragma unroll
                for (int si = 0; si < 3; ++si)
                    stage(b_src(st + 1, si), BOFF((st + 1) & 1, si));
            }
            // stage RA chunk st+3
            if (P == 0) {
                if (st >= 1 && st <= 8) stage(xs_src(st + 3), RAOF((st + 3) & 3, w));
            } else {
                if (st <= 8) {
                    const int k = st + 3;
                    stage((k < 4) ? xs_src(k) : xd_src(k - 4), RAOF(k & 3, w));
                }
            }
            // counted wait (retire all but newest N; per-wave in-order queue)
            if (P == 0) {
                if (st == 0)      asm volatile("s_waitcnt vmcnt(3)" ::: "memory");
                else if (st == 1) asm volatile("s_waitcnt vmcnt(4)" ::: "memory");
                else if (st <= 8) asm volatile("s_waitcnt vmcnt(5)" ::: "memory");
                else if (st == 9) asm volatile("s_waitcnt vmcnt(4)" ::: "memory");
                else if (st <= 18) asm volatile("s_waitcnt vmcnt(3)" ::: "memory");
                else              asm volatile("s_waitcnt vmcnt(0)" ::: "memory");
            } else {
                if (st == 0)      asm volatile("s_waitcnt vmcnt(6)" ::: "memory");
                else if (st <= 8) asm volatile("s_waitcnt vmcnt(5)" ::: "memory");
                else if (st == 9) asm volatile("s_waitcnt vmcnt(4)" ::: "memory");
                else if (st <= 18) asm volatile("s_waitcnt vmcnt(3)" ::: "memory");
                else              asm volatile("s_waitcnt vmcnt(0)" ::: "memory");
            }
            __builtin_amdgcn_sched_barrier(0);
            const bool dobar = (P == 0) ? (st == 0 || (st >= 4 && st <= 11)) : (st <= 11);
            if (dobar) {
                __builtin_amdgcn_s_barrier();
                __builtin_amdgcn_sched_barrier(0);
            }

            bf16x8 A[8];
            if (P == 0 && st < 4) {
#pragma unroll
                for (int g = 0; g < 8; ++g)
                    A[g] = *(const bf16x8*)(lds + HOFF(st, g) + laneoff);
            } else if (st < 12) {
#pragma unroll
                for (int g = 0; g < 8; ++g)
                    A[g] = *(const bf16x8*)(lds + RAOF(st & 3, g) + laneoff);
            } else if (st < 16) {
#pragma unroll
                for (int g = 0; g < 8; ++g)
                    A[g] = *(const bf16x8*)(lds + HOFF(st - 12, g) + laneoff);
            } else {
#pragma unroll
                for (int g = 0; g < 8; ++g)
                    A[g] = *(const bf16x8*)(lds + EOFF(st - 16, g) + laneoff);
            }
            bf16x8 B0 = *(const bf16x8*)(lds + BOFF(st & 1, 0) + laneoff);
            bf16x8 B1 = *(const bf16x8*)(lds + BOFF(st & 1, 1) + laneoff);
            bf16x8 B2 = *(const bf16x8*)(lds + BOFF(st & 1, 2) + laneoff);

            const bool hph = (st >= 12 && st < 16);
            __builtin_amdgcn_s_setprio(1);
            MFMA_ROW(0, B0);
            MFMA_ROW(1, B1);
            if (hph) { MFMA_ROW(3, B2); } else { MFMA_ROW(2, B2); }
            __builtin_amdgcn_s_setprio(0);
        }
    };

    // ================= PASS 0 prologue =================
#pragma unroll
    for (int k = 0; k < 4; ++k) stage(xs_src(k), HOFF(k, w));   // H prefill = original self
#pragma unroll
    for (int si = 0; si < 3; ++si) stage(b_src(0, si), BOFF(0, si));
    enc_fill(dtvS);
    asm volatile("s_waitcnt lgkmcnt(0)" ::: "memory");
    __builtin_amdgcn_sched_barrier(0);
    __builtin_amdgcn_s_barrier();          // publish ENC + meta
    __builtin_amdgcn_sched_barrier(0);

    run_pass(std::integral_constant<int, 0>{});

    // ================= transition =================
    __builtin_amdgcn_s_barrier();          // #1: all waves past H/ENC reads of P0
    __builtin_amdgcn_sched_barrier(0);

    const int j = w * 16 + c;
    const float br = b_ih[j] + b_hh[j];
    const float bz = b_ih[128 + j] + b_hh[128 + j];
    const float bi = b_ih[256 + j];
    const float bh = b_hh[256 + j];
    const int hcm = w >> 1, q2 = (j >> 3) & 3, bb = j & 7;

    // epilogue-0: read old h (bf16, LDS), gates, out_mem store, overwrite h in place
#pragma unroll
    for (int g = 0; g < 8; ++g) {
#pragma unroll
        for (int reg = 0; reg < 4; ++reg) {
            const int mloc = g * 16 + quad * 4 + reg;
            const long n = n0 + mloc;
            unsigned short* hp = (unsigned short*)(lds + HOFF(hcm, g)
                                 + ((q2 * 16 + quad * 4 + reg) << 4) + (bb << 1));
            float hv = bf2f(*hp);
            if (aS_l[mloc]) {
                const float r  = sigmoidf_(acc[0][g][reg] + br);
                const float z  = sigmoidf_(acc[1][g][reg] + bz);
                const float nn = tanhf_(acc[2][g][reg] + bi + r * (acc[3][g][reg] + bh));
                hv = (1.0f - z) * nn + z * hv;
                out_mem[(size_t)n * DIM_C + j] = hv;
            }
            *hp = f2bf(hv);
        }
    }

    // P1 prologue DMA (issue under epilogue/ENC shadow)
#pragma unroll
    for (int si = 0; si < 3; ++si) stage(b_src(0, si), BOFF(0, si));
#pragma unroll
    for (int k = 0; k < 3; ++k) stage(xs_src(k), RAOF(k, w));   // P1 chunks 0-2 = Xs self
    enc_fill(dtvD);
    asm volatile("s_waitcnt lgkmcnt(0)" ::: "memory");
    __builtin_amdgcn_sched_barrier(0);
    __builtin_amdgcn_s_barrier();          // #2: publish h_new + ENC(d)
    __builtin_amdgcn_sched_barrier(0);

#pragma unroll
    for (int s = 0; s < 4; ++s)
#pragma unroll
        for (int g = 0; g < 8; ++g) acc[s][g] = (f32x4){0.f, 0.f, 0.f, 0.f};

    // ================= PASS 1 =================
    run_pass(std::integral_constant<int, 1>{});

    // epilogue-1: blend h from H-LDS (post-pass0), store active-d nodes
#pragma unroll
    for (int g = 0; g < 8; ++g) {
#pragma unroll
        for (int reg = 0; reg < 4; ++reg) {
            const int mloc = g * 16 + quad * 4 + reg;
            const long n = n0 + mloc;
            if (aD_l[mloc]) {
                const unsigned short* hp = (const unsigned short*)(lds + HOFF(hcm, g)
                                           + ((q2 * 16 + quad * 4 + reg) << 4) + (bb << 1));
                const float hv = bf2f(*hp);
                const float r  = sigmoidf_(acc[0][g][reg] + br);
                const float z  = sigmoidf_(acc[1][g][reg] + bz);
                const float nn = tanhf_(acc[2][g][reg] + bi + r * (acc[3][g][reg] + bh));
                out_mem[(size_t)n * DIM_C + j] = (1.0f - z) * nn + z * hv;
            }
        }
    }
#undef MFMA_ROW
#undef MFMA_G
#undef RAOF
#undef BOFF
#undef HOFF
#undef EOFF
}

// =====================  FALLBACK (R2 fused) PATH  =====================
#define NODES_PB  32
#define LDSW      648
#define WROWS     512
#define NXF       640

__global__ void build_wall_kernel(const float* __restrict__ W_ih, const float* __restrict__ W_hh,
                                  unsigned short* __restrict__ Wall) {
    int i = blockIdx.x * 256 + threadIdx.x;
    if (i >= WROWS * NXF) return;
    int r = i / NXF, k = i - r * NXF;
    float v;
    if (r < 256)      v = (k < 512) ? W_ih[(long)r * DMSG_C + k] : W_hh[(long)r * DIM_C + (k - 512)];
    else if (r < 384) v = (k < 512) ? W_ih[(long)r * DMSG_C + k] : 0.0f;
    else              v = (k >= 512) ? W_hh[(long)(r - 128) * DIM_C + (k - 512)] : 0.0f;
    Wall[i] = f2bf(v);
}

template <int PASS>
__global__ __launch_bounds__(256) void gru_mfma_kernel(
    const float* __restrict__ memory, const float* __restrict__ last_update,
    const unsigned short* __restrict__ Wall,
    const float* __restrict__ b_ih, const float* __restrict__ b_hh,
    const float* __restrict__ edge_times, const float* __restrict__ edge_feat,
    const int* __restrict__ src, const int* __restrict__ dst,
    const int* __restrict__ idx,
    float* __restrict__ out_mem, float* __restrict__ out_lu)
{
    __shared__ __align__(16) unsigned short Xl[NODES_PB][LDSW];
    __shared__ int eidx[NODES_PB];
    const int t = threadIdx.x;
    const int base = blockIdx.x * NODES_PB;
    if (t < NODES_PB) eidx[t] = idx[base + t];
    __syncthreads();
    const int tt = t & 127;
    const int sh = t >> 7;
    const float wfreq = __expf(-0.16317532f * (float)tt);
    for (int s0 = 0; s0 < NODES_PB; s0 += 2) {
        const int s = s0 + sh;
        const int n = base + s;
        const int e = eidx[s];
        const int eu = (e >= 0) ? e : 0;
        const int other = (PASS == 0) ? dst[eu] : src[eu];
        const float mself = memory[(long)n * DIM_C + tt];
        const float moth  = memory[(long)other * DIM_C + tt];
        const float ef    = edge_feat[(long)eu * DIM_C + tt];
        const float dt    = edge_times[eu] - last_update[n];
        const float enc   = __cosf(dt * wfreq);
        const float hv    = (PASS == 0) ? mself : out_mem[(long)n * DIM_C + tt];
        Xl[s][tt]       = f2bf(mself);
        Xl[s][128 + tt] = f2bf(moth);
        Xl[s][256 + tt] = f2bf(ef);
        Xl[s][384 + tt] = f2bf(enc);
        Xl[s][512 + tt] = f2bf(hv);
    }
    __syncthreads();
    const int w = t >> 6, lane = t & 63;
    const int quad = lane >> 4, c = lane & 15;
    f32x4 acc[8][2];
#pragma unroll
    for (int i = 0; i < 8; ++i)
#pragma unroll
        for (int mt = 0; mt < 2; ++mt) acc[i][mt] = (f32x4){0.f, 0.f, 0.f, 0.f};
    const unsigned short* wrow[8];
#pragma unroll
    for (int i = 0; i < 8; ++i)
        wrow[i] = Wall + (long)((w + 4 * i) * 16 + c) * NXF + quad * 8;
    for (int kk = 0; kk < 16; ++kk) {
        const int k0 = kk * 32;
        bf16x8 a0 = *(const bf16x8*)&Xl[c][k0 + quad * 8];
        bf16x8 a1 = *(const bf16x8*)&Xl[16 + c][k0 + quad * 8];
#pragma unroll
        for (int i = 0; i < 6; ++i) {
            bf16x8 b = *(const bf16x8*)(wrow[i] + k0);
            acc[i][0] = __builtin_amdgcn_mfma_f32_16x16x32_bf16(a0, b, acc[i][0], 0, 0, 0);
            acc[i][1] = __builtin_amdgcn_mfma_f32_16x16x32_bf16(a1, b, acc[i][1], 0, 0, 0);
        }
    }
    for (int kk = 16; kk < 20; ++kk) {
        const int k0 = kk * 32;
        bf16x8 a0 = *(const bf16x8*)&Xl[c][k0 + quad * 8];
        bf16x8 a1 = *(const bf16x8*)&Xl[16 + c][k0 + quad * 8];
#pragma unroll
        for (int ii = 0; ii < 6; ++ii) {
            const int i = (ii < 4) ? ii : ii + 2;
            bf16x8 b = *(const bf16x8*)(wrow[i] + k0);
            acc[i][0] = __builtin_amdgcn_mfma_f32_16x16x32_bf16(a0, b, acc[i][0], 0, 0, 0);
            acc[i][1] = __builtin_amdgcn_mfma_f32_16x16x32_bf16(a1, b, acc[i][1], 0, 0, 0);
        }
    }
    const float* hsrc = (PASS == 0) ? memory : out_mem;
#pragma unroll
    for (int p = 0; p < 2; ++p) {
        const int j = (w + 4 * p) * 16 + c;
        const float br = b_ih[j] + b_hh[j];
        const float bz = b_ih[128 + j] + b_hh[128 + j];
        const float bi = b_ih[256 + j];
        const float bh = b_hh[256 + j];
#pragma unroll
        for (int mt = 0; mt < 2; ++mt) {
#pragma unroll
            for (int reg = 0; reg < 4; ++reg) {
                const int ml = mt * 16 + quad * 4 + reg;
                const int n = base + ml;
                const int e = eidx[ml];
                const float h = hsrc[(long)n * DIM_C + j];
                if (e >= 0) {
                    const float r  = sigmoidf_(acc[p][mt][reg] + br);
                    const float z  = sigmoidf_(acc[p + 2][mt][reg] + bz);
                    const float nn = tanhf_(acc[p + 4][mt][reg] + bi + r * (acc[p + 6][mt][reg] + bh));
                    out_mem[(long)n * DIM_C + j] = (1.0f - z) * nn + z * h;
                } else if (PASS == 0) {
                    out_mem[(long)n * DIM_C + j] = h;
                }
            }
        }
    }
    if (t < NODES_PB) {
        const int n = base + t;
        const int e = eidx[t];
        if (e >= 0)         out_lu[n] = edge_times[e];
        else if (PASS == 0) out_lu[n] = last_update[n];
    }
}

// =====================  LAUNCH  =====================
extern "C" void kernel_launch(void* const* d_in, const int* in_sizes, int n_in,
                              void* d_out, int out_size, void* d_ws, size_t ws_size,
                              hipStream_t stream) {
    const float* memory      = (const float*)d_in[0];
    const float* last_update = (const float*)d_in[1];
    const float* W_ih        = (const float*)d_in[2];
    const float* W_hh        = (const float*)d_in[3];
    const float* b_ih        = (const float*)d_in[4];
    const float* b_hh        = (const float*)d_in[5];
    const float* edge_times  = (const float*)d_in[6];
    const float* edge_feat   = (const float*)d_in[7];
    const int*   src         = (const int*)d_in[8];
    const int*   dst         = (const int*)d_in[9];

    float* out_mem = (float*)d_out;
    float* out_lu  = out_mem + (size_t)N_NODES_C * DIM_C;

    // ws layout (main path)
    const size_t sIdx  = (size_t)NODES_PAD * 4;            // 400384 B each
    const size_t sDt   = (size_t)NODES_PAD * 4;
    const size_t sWall = (size_t)32 * 20 * 1024;           // 655360 B
    const size_t sXs   = (size_t)GROUPS_PAD * 12 * 1024;   // 76.9 MB
    const size_t sXd   = (size_t)GROUPS_PAD * 8 * 1024;    // 51.3 MB
    const size_t oIdxS = 0, oIdxD = oIdxS + sIdx, oDtS = oIdxD + sIdx, oDtD = oDtS + sDt;
    const size_t oWall = oDtD + sDt, oXs = oWall + sWall, oXd = oXs + sXs;
    const size_t need  = oXd + sXd;                        // ~131 MB

    if (ws_size >= need) {
        int* idx_s = (int*)((char*)d_ws + oIdxS);
        int* idx_d = (int*)((char*)d_ws + oIdxD);
        float* dt_s = (float*)((char*)d_ws + oDtS);
        float* dt_d = (float*)((char*)d_ws + oDtD);
        unsigned short* Wsw = (unsigned short*)((char*)d_ws + oWall);
        unsigned short* Xs  = (unsigned short*)((char*)d_ws + oXs);
        unsigned short* Xd  = (unsigned short*)((char*)d_ws + oXd);

        hipMemsetAsync(d_ws, 0xFF, 2 * sIdx, stream);      // idx arrays = -1
        scatter_last_kernel<<<(N_EDGES_C + 255) / 256, 256, 0, stream>>>(src, dst, idx_s, idx_d);
        build_wallsw_kernel<<<160, 256, 0, stream>>>(W_ih, W_hh, Wsw);
        gather_kernel<<<N_NODES_C / 16, 256, 0, stream>>>(
            memory, last_update, edge_times, edge_feat, src, dst,
            idx_s, idx_d, dt_s, dt_d, Xs, Xd, out_mem, out_lu);
        gemm_fused_kernel<<<GROUPS_PAD / 8, 512, 0, stream>>>(
            Wsw, b_ih, b_hh, Xs, Xd, dt_s, dt_d, idx_s, idx_d, out_mem);
    } else {
        // R2 fused fallback (needs ~1.5 MB ws)
        int* idx_s = (int*)d_ws;
        int* idx_d = idx_s + N_NODES_C;
        unsigned short* Wall = (unsigned short*)((char*)d_ws + 2 * N_NODES_C * sizeof(int));
        hipMemsetAsync(d_ws, 0xFF, 2 * N_NODES_C * sizeof(int), stream);
        scatter_last_kernel<<<(N_EDGES_C + 255) / 256, 256, 0, stream>>>(src, dst, idx_s, idx_d);
        build_wall_kernel<<<(WROWS * NXF + 255) / 256, 256, 0, stream>>>(W_ih, W_hh, Wall);
        gru_mfma_kernel<0><<<N_NODES_C / NODES_PB, 256, 0, stream>>>(
            memory, last_update, Wall, b_ih, b_hh, edge_times, edge_feat,
            src, dst, idx_s, out_mem, out_lu);
        gru_mfma_kernel<1><<<N_NODES_C / NODES_PB, 256, 0, stream>>>(
            memory, last_update, Wall, b_ih, b_hh, edge_times, edge_feat,
            src, dst, idx_d, out_mem, out_lu);
    }
}

// Round 12
// 458.583 us; speedup vs baseline: 1.2875x; 1.2875x over previous
//
#include <hip/hip_runtime.h>
#include <math.h>

// Problem constants (match reference file)
#define N_NODES_C 100000
#define DIM_C     128
#define DMSG_C    512
#define N_EDGES_C 200000

// GEMM geometry: 128 nodes/block (8 node-groups of 16), 512 gate rows = 32 tiles
#define GROUPS_PAD 6256            // 782 gemm blocks * 8 groups
#define NODES_PAD  (GROUPS_PAD*16) // 100096

typedef __attribute__((ext_vector_type(8))) __bf16 bf16x8;
typedef __attribute__((ext_vector_type(4))) float  f32x4;

__device__ __forceinline__ float sigmoidf_(float x) { return 1.0f / (1.0f + __expf(-x)); }
// fast tanh: 1 - 2/(e^{2x}+1); exact at +/-inf, ~1e-7 abs err mid-range (<< bf16 gemm noise)
__device__ __forceinline__ float tanhf_(float x) { return 1.0f - 2.0f / (__expf(2.0f * x) + 1.0f); }
__device__ __forceinline__ unsigned short f2bf(float x) {
    union { float f; unsigned u; } v; v.f = x;
    unsigned r = v.u + 0x7FFFu + ((v.u >> 16) & 1u);   // RNE
    return (unsigned short)(r >> 16);
}
__device__ __forceinline__ void st8(void* p, float4 lo, float4 hi) {
    union { bf16x8 v; unsigned short u[8]; } r;
    r.u[0] = f2bf(lo.x); r.u[1] = f2bf(lo.y); r.u[2] = f2bf(lo.z); r.u[3] = f2bf(lo.w);
    r.u[4] = f2bf(hi.x); r.u[5] = f2bf(hi.y); r.u[6] = f2bf(hi.z); r.u[7] = f2bf(hi.w);
    *(bf16x8*)p = r.v;
}

// ---- last occurrence of each node in edge order ----
__global__ void scatter_last_kernel(const int* __restrict__ src, const int* __restrict__ dst,
                                    int* __restrict__ idx_s, int* __restrict__ idx_d) {
    int e = blockIdx.x * blockDim.x + threadIdx.x;
    if (e < N_EDGES_C) {
        atomicMax(&idx_s[src[e]], e);
        atomicMax(&idx_d[dst[e]], e);
    }
}

// =====================  MAIN (split) PATH  =====================
// Wsw[tile][kk][lane][8]: B-fragment order. tile T holds packed gate rows T*16+(l&15):
//   tiles 0-7 r, 8-15 z, 16-23 i_n (W_ih), 24-31 h_n (W_hh rows 256..383)
// K map: 0..127 self, 128..255 other, 256..383 ef, 384..511 enc, 512..639 h
__global__ void build_wallsw_kernel(const float* __restrict__ W_ih, const float* __restrict__ W_hh,
                                    unsigned short* __restrict__ Wsw) {
    int id = blockIdx.x * 256 + threadIdx.x;           // 32*20*64 = 40960
    if (id >= 32 * 20 * 64) return;
    int tile = id / 1280, r = id - tile * 1280, kk = r >> 6, l = r & 63;
    int pr = tile * 16 + (l & 15);
    int k0 = kk * 32 + ((l >> 4) & 3) * 8;
    float v[8];
#pragma unroll
    for (int j = 0; j < 8; ++j) {
        int k = k0 + j;
        if (pr < 256)      v[j] = (k < 512) ? W_ih[(long)pr * DMSG_C + k] : W_hh[(long)pr * DIM_C + (k - 512)];
        else if (pr < 384) v[j] = (k < 512) ? W_ih[(long)pr * DMSG_C + k] : 0.0f;
        else               v[j] = (k >= 512) ? W_hh[(long)(pr - 128) * DIM_C + (k - 512)] : 0.0f;
    }
    union { bf16x8 bv; unsigned short u[8]; } o;
#pragma unroll
    for (int j = 0; j < 8; ++j) o.u[j] = f2bf(v[j]);
    *(bf16x8*)((char*)Wsw + ((size_t)(tile * 20 + kk) << 10) + ((size_t)l << 4)) = o.bv;
}

// Gather: 16 nodes/block. Builds Xs (12 chunks: self|otherS|efS) and Xd
// (8 chunks: otherD|efD) in A-frag-swizzled bf16, dt arrays, out_lu, and the
// inactive-pass0 copy of memory into out_mem.
__global__ __launch_bounds__(256) void gather_kernel(
    const float* __restrict__ memory, const float* __restrict__ last_update,
    const float* __restrict__ edge_times, const float* __restrict__ edge_feat,
    const int* __restrict__ src, const int* __restrict__ dst,
    const int* __restrict__ idx_s, const int* __restrict__ idx_d,
    float* __restrict__ dt_s, float* __restrict__ dt_d,
    unsigned short* __restrict__ Xs, unsigned short* __restrict__ Xd,
    float* __restrict__ out_mem, float* __restrict__ out_lu)
{
    __shared__ int es_l[16], ed_l[16], os_l[16], od_l[16];
    const int t = threadIdx.x;
    const int base = blockIdx.x * 16;
    if (t < 16) {
        const int n = base + t;
        const int es = idx_s[n], ed = idx_d[n];
        const int eus = es < 0 ? 0 : es, eud = ed < 0 ? 0 : ed;
        es_l[t] = es; ed_l[t] = ed;
        os_l[t] = dst[eus]; od_l[t] = src[eud];
        const float lun = last_update[n];
        const float ts = edge_times[eus], td = edge_times[eud];
        dt_s[n] = ts - lun; dt_d[n] = td - lun;
        out_lu[n] = (ed >= 0) ? td : ((es >= 0) ? ts : lun);
    }
    __syncthreads();
    const int m = t & 15, q = t >> 4;                  // node-in-block, col-chunk (8 cols)
    const int n = base + m;
    const size_t g = blockIdx.x;                       // node-group == block
    const int es = es_l[m];
    const int eus = (es < 0) ? 0 : es;
    const int eud = (ed_l[m] < 0) ? 0 : ed_l[m];
    const float4* self_p = (const float4*)(memory + (size_t)n * DIM_C + q * 8);
    const float4* oS_p   = (const float4*)(memory + (size_t)os_l[m] * DIM_C + q * 8);
    const float4* oD_p   = (const float4*)(memory + (size_t)od_l[m] * DIM_C + q * 8);
    const float4* eS_p   = (const float4*)(edge_feat + (size_t)eus * DIM_C + q * 8);
    const float4* eD_p   = (const float4*)(edge_feat + (size_t)eud * DIM_C + q * 8);
    float4 s0 = self_p[0], s1 = self_p[1];
    float4 a0 = oS_p[0],   a1 = oS_p[1];
    float4 b0 = oD_p[0],   b1 = oD_p[1];
    float4 c0 = eS_p[0],   c1 = eS_p[1];
    float4 d0 = eD_p[0],   d1 = eD_p[1];
    const int kkq = q >> 2;
    const size_t laneoff = (size_t)(((q & 3) * 16 + m)) << 4;
    char* XsB = (char*)Xs; char* XdB = (char*)Xd;
#define XOFFS(kk) ((((g * 12) + (kk)) << 10) + laneoff)
#define XOFFD(kk) ((((g * 8) + (kk)) << 10) + laneoff)
    st8(XsB + XOFFS(kkq),     s0, s1);
    st8(XsB + XOFFS(4 + kkq), a0, a1);
    st8(XsB + XOFFS(8 + kkq), c0, c1);
    st8(XdB + XOFFD(kkq),     b0, b1);
    st8(XdB + XOFFD(4 + kkq), d0, d1);
#undef XOFFS
#undef XOFFD
    if (es < 0) {   // inactive in pass0: seed out_mem with original memory row
        float4* op = (float4*)(out_mem + (size_t)n * DIM_C + q * 8);
        op[0] = s0; op[1] = s1;
    }
}

// GEMM+GRU pass, R13 (= R11 + coalesced Hmir writes).
// 512 thr = 8 waves over 128 nodes (8 groups); wave w owns gate tiles
// {w, w+8, w+16, w+24}; acc[4 gate][8 group]; B wave-private 3 tiles/step.
//
// R11 post-mortem: epilogue-0's scattered 2-byte Hmir stores caused RMW
// fetches + dirty-partial writebacks (+25 MB FETCH, WRITE 43->68 MB,
// +38 us/pass). R13 fix: h_new staged in LDS (reusing the ENC region,
// dead after step 19) and then copied to Hmir as a contiguous 32 KB
// full-line stream (block's 32 chunks are contiguous at g0*4).
//
// LDS 144 KB: RA 4-deep [sl4][g8][1KB] @0; PA persistent self [k4][g8][1KB]
// @32K (pass0 only); B 2-deep [buf2][w8][si3][1KB] @64K; ENC/HST [32KB] @112K.
// PASS 0: A chunks 0..11 (0-3 -> PA, 4-11 -> RA); steps 12-15 (H) read PA
//   (h == original memory == self); steps 12..19 barrier-free.
//   vmcnt: st<=9:5, st10:4, st11..18:3, st19:0. Barriers st<=11.
// PASS 1: A chunks 0..15 -> RA (0-3 Xs self, 4-11 Xd, 12-15 Hmir); barriers
//   st<=15. vmcnt: st<=13:5, st14:4, st15..18:3, st19:0.
template <int PASS>
__global__ __launch_bounds__(512, 2) void gemm_pass_kernel(
    const float* __restrict__ memory,
    const unsigned short* __restrict__ Wsw,
    const float* __restrict__ b_ih, const float* __restrict__ b_hh,
    const unsigned short* __restrict__ Xs, const unsigned short* __restrict__ Xd,
    unsigned short* __restrict__ Hmir,
    const float* __restrict__ dtp, const int* __restrict__ idxp,
    float* __restrict__ out_mem)
{
    __shared__ __align__(1024) char lds[147456];
    const int t = threadIdx.x;
    const int w = t >> 6, lane = t & 63, quad = lane >> 4, c = lane & 15;
    const long g0 = (long)blockIdx.x * 8;
    const char* XsB = (const char*)Xs;
    const char* XdB = (const char*)Xd;
    const char* HmB = (const char*)Hmir;
    const char* Wb  = (const char*)Wsw;
    const size_t laneoff = (size_t)lane << 4;

#define RAOF(sl, g)  ((((sl) * 8) + (g)) << 10)                        // 32 KB @0
#define PAOF(k, g)   (32768 + ((((k) * 8) + (g)) << 10))               // 32 KB @32K
#define BOFF(buf, si) (65536 + ((((buf) * 8 + w) * 3 + (si)) << 10))   // 48 KB @64K
#define EOFF(ec, g)  (114688 + ((((ec) * 8) + (g)) << 10))             // 32 KB @112K
#define HSTOF(g, k)  (114688 + ((((g) * 4) + (k)) << 10))              // HST aliases ENC

    // ---- dt loads for this wave's ENC share (retire before staging: exact vmcnt) ----
    const int ecw = w & 3, gh = (w >> 2) * 4;
    float dtv[4];
#pragma unroll
    for (int g2 = 0; g2 < 4; ++g2) dtv[g2] = dtp[(g0 + gh + g2) * 16 + c];
    asm volatile("s_waitcnt vmcnt(0)" ::: "memory");
    __builtin_amdgcn_sched_barrier(0);

    auto stage = [&](const char* gsrc, int ldsoff) {
        __builtin_amdgcn_global_load_lds(
            (const __attribute__((address_space(1))) void*)(gsrc + laneoff),
            (__attribute__((address_space(3))) void*)(lds + ldsoff), 16, 0, 0);
    };
    // A source for data-step k
    auto a_src = [&](int k) -> const char* {
        if (PASS == 0) return XsB + (((g0 + w) * 12 + k) << 10);           // k in 0..11
        if (k < 4)  return XsB + (((g0 + w) * 12 + k) << 10);              // self (immutable)
        if (k < 12) return XdB + (((g0 + w) * 8 + (k - 4)) << 10);         // otherD/efD
        return HmB + (((g0 + w) * 4 + (k - 12)) << 10);                    // post-pass0 h
    };
    auto a_dst = [&](int k) -> int {
        return (PASS == 0 && k < 4) ? PAOF(k, w) : RAOF(k & 3, w);
    };
    // B tile for step k, slot-index si (0:r, 1:z, 2: i or hn)
    auto b_src = [&](int k, int si) -> const char* {
        const bool hph = (k >= 12 && k < 16);
        const int tile = (si < 2) ? (w + 8 * si) : (hph ? (w + 24) : (w + 16));
        const int kk = (k < 12) ? k : (hph ? k + 4 : k - 4);
        return Wb + ((size_t)(tile * 20 + kk) << 10);
    };
    constexpr int ALAST = (PASS == 0) ? 11 : 15;   // last A-staged chunk

    f32x4 acc[4][8];
#pragma unroll
    for (int s = 0; s < 4; ++s)
#pragma unroll
        for (int g = 0; g < 8; ++g) acc[s][g] = (f32x4){0.f, 0.f, 0.f, 0.f};

    // ---- prologue: issue [B(0)x3, A(0), A(1)] then compute ENC (DMA shadow) ----
#pragma unroll
    for (int si = 0; si < 3; ++si) stage(b_src(0, si), BOFF(0, si));
    stage(a_src(0), a_dst(0));
    stage(a_src(1), a_dst(1));

    {   // ENC fragments: wave w fills chunk (w&3), groups gh..gh+3.
        const int f0 = ecw * 32 + quad * 8;
        float wf[8];
#pragma unroll
        for (int j = 0; j < 8; ++j) wf[j] = __expf(-0.16317532f * (float)(f0 + j));
#pragma unroll
        for (int g2 = 0; g2 < 4; ++g2) {
            union { bf16x8 v; unsigned short u[8]; } r;
#pragma unroll
            for (int j = 0; j < 8; ++j) r.u[j] = f2bf(__cosf(dtv[g2] * wf[j]));
            *(bf16x8*)(lds + EOFF(ecw, gh + g2) + laneoff) = r.v;
        }
    }
    asm volatile("s_waitcnt lgkmcnt(0)" ::: "memory");   // ENC ds_writes done
    __builtin_amdgcn_sched_barrier(0);
    __builtin_amdgcn_s_barrier();                        // publish ENC (no vm drain)
    __builtin_amdgcn_sched_barrier(0);

#define MFMA_G(s, Bv, g) \
    acc[s][g] = __builtin_amdgcn_mfma_f32_16x16x32_bf16(A[g], Bv, acc[s][g], 0, 0, 0)
#define MFMA_ROW(s, Bv) \
    MFMA_G(s, Bv, 0); MFMA_G(s, Bv, 1); MFMA_G(s, Bv, 2); MFMA_G(s, Bv, 3); \
    MFMA_G(s, Bv, 4); MFMA_G(s, Bv, 5); MFMA_G(s, Bv, 6); MFMA_G(s, Bv, 7)

#pragma unroll
    for (int st = 0; st < 20; ++st) {
        // stage next: B(st+1) x3 (if any), A(st+2) (if <= ALAST)
        if (st + 1 <= 19) {
#pragma unroll
            for (int si = 0; si < 3; ++si)
                stage(b_src(st + 1, si), BOFF((st + 1) & 1, si));
        }
        if (st + 2 <= ALAST) stage(a_src(st + 2), a_dst(st + 2));

        // static counted wait (retire A(st)+B(st); leave newer in flight)
        if (PASS == 0) {
            if (st <= 9)       asm volatile("s_waitcnt vmcnt(5)" ::: "memory");
            else if (st == 10) asm volatile("s_waitcnt vmcnt(4)" ::: "memory");
            else if (st <= 18) asm volatile("s_waitcnt vmcnt(3)" ::: "memory");
            else               asm volatile("s_waitcnt vmcnt(0)" ::: "memory");
        } else {
            if (st <= 13)      asm volatile("s_waitcnt vmcnt(5)" ::: "memory");
            else if (st == 14) asm volatile("s_waitcnt vmcnt(4)" ::: "memory");
            else if (st <= 18) asm volatile("s_waitcnt vmcnt(3)" ::: "memory");
            else               asm volatile("s_waitcnt vmcnt(0)" ::: "memory");
        }
        __builtin_amdgcn_sched_barrier(0);
        // publish A(st): P0 needs barriers only while fresh A arrives (st<=11);
        // P0 steps 12-19 and P1 steps 16-19 are barrier-free (B wave-private).
        if ((PASS == 0 && st <= 11) || (PASS == 1 && st <= 15)) {
            __builtin_amdgcn_s_barrier();
            __builtin_amdgcn_sched_barrier(0);
        }

        bf16x8 A[8];
        if (st < 16) {
            if (PASS == 0 && st < 4) {
#pragma unroll
                for (int g = 0; g < 8; ++g)
                    A[g] = *(const bf16x8*)(lds + PAOF(st, g) + laneoff);
            } else if (PASS == 0 && st >= 12) {
#pragma unroll
                for (int g = 0; g < 8; ++g)
                    A[g] = *(const bf16x8*)(lds + PAOF(st - 12, g) + laneoff);
            } else {
#pragma unroll
                for (int g = 0; g < 8; ++g)
                    A[g] = *(const bf16x8*)(lds + RAOF(st & 3, g) + laneoff);
            }
        } else {
#pragma unroll
            for (int g = 0; g < 8; ++g)
                A[g] = *(const bf16x8*)(lds + EOFF(st - 16, g) + laneoff);
        }
        bf16x8 B0 = *(const bf16x8*)(lds + BOFF(st & 1, 0) + laneoff);
        bf16x8 B1 = *(const bf16x8*)(lds + BOFF(st & 1, 1) + laneoff);
        bf16x8 B2 = *(const bf16x8*)(lds + BOFF(st & 1, 2) + laneoff);

        const bool hph = (st >= 12 && st < 16);
        __builtin_amdgcn_s_setprio(1);
        MFMA_ROW(0, B0);
        MFMA_ROW(1, B1);
        if (hph) { MFMA_ROW(3, B2); } else { MFMA_ROW(2, B2); }
        __builtin_amdgcn_s_setprio(0);
    }

    // ---- Epilogue: lane owns dim j = w*16+c for nodes (g0+g)*16 + quad*4 + reg ----
    const float* hsrc = (PASS == 0) ? memory : out_mem;
    const int j = w * 16 + c;
    const float br = b_ih[j] + b_hh[j];
    const float bz = b_ih[128 + j] + b_hh[128 + j];
    const float bi = b_ih[256 + j];
    const float bh = b_hh[256 + j];
    const int kkm = j >> 5, q2 = (j >> 3) & 3, bb = j & 7;

    int ebuf[8][4];
#pragma unroll
    for (int g = 0; g < 8; ++g)
#pragma unroll
        for (int reg = 0; reg < 4; ++reg) {
            const long n = (g0 + g) * 16 + quad * 4 + reg;
            ebuf[g][reg] = (n < N_NODES_C) ? idxp[n] : -1;
        }
    float hbuf[8][4];
#pragma unroll
    for (int g = 0; g < 8; ++g)
#pragma unroll
        for (int reg = 0; reg < 4; ++reg) {
            const long n = (g0 + g) * 16 + quad * 4 + reg;
            hbuf[g][reg] = hsrc[(size_t)(n < N_NODES_C ? n : 0) * DIM_C + j];
        }

    if (PASS == 0) {
        // ENC region is dead only after ALL waves pass st19; protect HST reuse.
        asm volatile("s_waitcnt lgkmcnt(0)" ::: "memory");
        __builtin_amdgcn_sched_barrier(0);
        __builtin_amdgcn_s_barrier();
        __builtin_amdgcn_sched_barrier(0);
    }

#pragma unroll
    for (int g = 0; g < 8; ++g) {
#pragma unroll
        for (int reg = 0; reg < 4; ++reg) {
            const long n = (g0 + g) * 16 + quad * 4 + reg;
            float hv = hbuf[g][reg];
            if (n < N_NODES_C && ebuf[g][reg] >= 0) {
                const float r  = sigmoidf_(acc[0][g][reg] + br);
                const float z  = sigmoidf_(acc[1][g][reg] + bz);
                const float nn = tanhf_(acc[2][g][reg] + bi + r * (acc[3][g][reg] + bh));
                hv = (1.0f - z) * nn + z * hv;
                out_mem[(size_t)n * DIM_C + j] = hv;
            }
            if (PASS == 0) {
                // stage h (post-pass0 value; == original memory when inactive)
                // into LDS in Hmir chunk layout; defined values even for padded
                // nodes (hbuf clamped to row 0).
                *(unsigned short*)(lds + HSTOF(g, kkm)
                                   + ((q2 * 16 + quad * 4 + reg) << 4) + (bb << 1)) = f2bf(hv);
            }
        }
    }

    if (PASS == 0) {
        // coalesced HST -> Hmir copy: block's 32 chunks are contiguous at g0*4.
        asm volatile("s_waitcnt lgkmcnt(0)" ::: "memory");
        __builtin_amdgcn_sched_barrier(0);
        __builtin_amdgcn_s_barrier();
        __builtin_amdgcn_sched_barrier(0);
        char* hmDst = (char*)Hmir + ((size_t)(g0 * 4) << 10);
#pragma unroll
        for (int it = 0; it < 4; ++it) {
            const int o = it * 8192 + t * 16;
            *(float4*)(hmDst + o) = *(const float4*)(lds + 114688 + o);
        }
    }
#undef MFMA_ROW
#undef MFMA_G
#undef RAOF
#undef PAOF
#undef BOFF
#undef EOFF
#undef HSTOF
}

// =====================  FALLBACK (R2 fused) PATH  =====================
#define NODES_PB  32
#define LDSW      648
#define WROWS     512
#define NXF       640

__global__ void build_wall_kernel(const float* __restrict__ W_ih, const float* __restrict__ W_hh,
                                  unsigned short* __restrict__ Wall) {
    int i = blockIdx.x * 256 + threadIdx.x;
    if (i >= WROWS * NXF) return;
    int r = i / NXF, k = i - r * NXF;
    float v;
    if (r < 256)      v = (k < 512) ? W_ih[(long)r * DMSG_C + k] : W_hh[(long)r * DIM_C + (k - 512)];
    else if (r < 384) v = (k < 512) ? W_ih[(long)r * DMSG_C + k] : 0.0f;
    else              v = (k >= 512) ? W_hh[(long)(r - 128) * DIM_C + (k - 512)] : 0.0f;
    Wall[i] = f2bf(v);
}

template <int PASS>
__global__ __launch_bounds__(256) void gru_mfma_kernel(
    const float* __restrict__ memory, const float* __restrict__ last_update,
    const unsigned short* __restrict__ Wall,
    const float* __restrict__ b_ih, const float* __restrict__ b_hh,
    const float* __restrict__ edge_times, const float* __restrict__ edge_feat,
    const int* __restrict__ src, const int* __restrict__ dst,
    const int* __restrict__ idx,
    float* __restrict__ out_mem, float* __restrict__ out_lu)
{
    __shared__ __align__(16) unsigned short Xl[NODES_PB][LDSW];
    __shared__ int eidx[NODES_PB];
    const int t = threadIdx.x;
    const int base = blockIdx.x * NODES_PB;
    if (t < NODES_PB) eidx[t] = idx[base + t];
    __syncthreads();
    const int tt = t & 127;
    const int sh = t >> 7;
    const float wfreq = __expf(-0.16317532f * (float)tt);
    for (int s0 = 0; s0 < NODES_PB; s0 += 2) {
        const int s = s0 + sh;
        const int n = base + s;
        const int e = eidx[s];
        const int eu = (e >= 0) ? e : 0;
        const int other = (PASS == 0) ? dst[eu] : src[eu];
        const float mself = memory[(long)n * DIM_C + tt];
        const float moth  = memory[(long)other * DIM_C + tt];
        const float ef    = edge_feat[(long)eu * DIM_C + tt];
        const float dt    = edge_times[eu] - last_update[n];
        const float enc   = __cosf(dt * wfreq);
        const float hv    = (PASS == 0) ? mself : out_mem[(long)n * DIM_C + tt];
        Xl[s][tt]       = f2bf(mself);
        Xl[s][128 + tt] = f2bf(moth);
        Xl[s][256 + tt] = f2bf(ef);
        Xl[s][384 + tt] = f2bf(enc);
        Xl[s][512 + tt] = f2bf(hv);
    }
    __syncthreads();
    const int w = t >> 6, lane = t & 63;
    const int quad = lane >> 4, c = lane & 15;
    f32x4 acc[8][2];
#pragma unroll
    for (int i = 0; i < 8; ++i)
#pragma unroll
        for (int mt = 0; mt < 2; ++mt) acc[i][mt] = (f32x4){0.f, 0.f, 0.f, 0.f};
    const unsigned short* wrow[8];
#pragma unroll
    for (int i = 0; i < 8; ++i)
        wrow[i] = Wall + (long)((w + 4 * i) * 16 + c) * NXF + quad * 8;
    for (int kk = 0; kk < 16; ++kk) {
        const int k0 = kk * 32;
        bf16x8 a0 = *(const bf16x8*)&Xl[c][k0 + quad * 8];
        bf16x8 a1 = *(const bf16x8*)&Xl[16 + c][k0 + quad * 8];
#pragma unroll
        for (int i = 0; i < 6; ++i) {
            bf16x8 b = *(const bf16x8*)(wrow[i] + k0);
            acc[i][0] = __builtin_amdgcn_mfma_f32_16x16x32_bf16(a0, b, acc[i][0], 0, 0, 0);
            acc[i][1] = __builtin_amdgcn_mfma_f32_16x16x32_bf16(a1, b, acc[i][1], 0, 0, 0);
        }
    }
    for (int kk = 16; kk < 20; ++kk) {
        const int k0 = kk * 32;
        bf16x8 a0 = *(const bf16x8*)&Xl[c][k0 + quad * 8];
        bf16x8 a1 = *(const bf16x8*)&Xl[16 + c][k0 + quad * 8];
#pragma unroll
        for (int ii = 0; ii < 6; ++ii) {
            const int i = (ii < 4) ? ii : ii + 2;
            bf16x8 b = *(const bf16x8*)(wrow[i] + k0);
            acc[i][0] = __builtin_amdgcn_mfma_f32_16x16x32_bf16(a0, b, acc[i][0], 0, 0, 0);
            acc[i][1] = __builtin_amdgcn_mfma_f32_16x16x32_bf16(a1, b, acc[i][1], 0, 0, 0);
        }
    }
    const float* hsrc = (PASS == 0) ? memory : out_mem;
#pragma unroll
    for (int p = 0; p < 2; ++p) {
        const int j = (w + 4 * p) * 16 + c;
        const float br = b_ih[j] + b_hh[j];
        const float bz = b_ih[128 + j] + b_hh[128 + j];
        const float bi = b_ih[256 + j];
        const float bh = b_hh[256 + j];
#pragma unroll
        for (int mt = 0; mt < 2; ++mt) {
#pragma unroll
            for (int reg = 0; reg < 4; ++reg) {
                const int ml = mt * 16 + quad * 4 + reg;
                const int n = base + ml;
                const int e = eidx[ml];
                const float h = hsrc[(long)n * DIM_C + j];
                if (e >= 0) {
                    const float r  = sigmoidf_(acc[p][mt][reg] + br);
                    const float z  = sigmoidf_(acc[p + 2][mt][reg] + bz);
                    const float nn = tanhf_(acc[p + 4][mt][reg] + bi + r * (acc[p + 6][mt][reg] + bh));
                    out_mem[(long)n * DIM_C + j] = (1.0f - z) * nn + z * h;
                } else if (PASS == 0) {
                    out_mem[(long)n * DIM_C + j] = h;
                }
            }
        }
    }
    if (t < NODES_PB) {
        const int n = base + t;
        const int e = eidx[t];
        if (e >= 0)         out_lu[n] = edge_times[e];
        else if (PASS == 0) out_lu[n] = last_update[n];
    }
}

// =====================  LAUNCH  =====================
extern "C" void kernel_launch(void* const* d_in, const int* in_sizes, int n_in,
                              void* d_out, int out_size, void* d_ws, size_t ws_size,
                              hipStream_t stream) {
    const float* memory      = (const float*)d_in[0];
    const float* last_update = (const float*)d_in[1];
    const float* W_ih        = (const float*)d_in[2];
    const float* W_hh        = (const float*)d_in[3];
    const float* b_ih        = (const float*)d_in[4];
    const float* b_hh        = (const float*)d_in[5];
    const float* edge_times  = (const float*)d_in[6];
    const float* edge_feat   = (const float*)d_in[7];
    const int*   src         = (const int*)d_in[8];
    const int*   dst         = (const int*)d_in[9];

    float* out_mem = (float*)d_out;
    float* out_lu  = out_mem + (size_t)N_NODES_C * DIM_C;

    // ws layout (main path)
    const size_t sIdx  = (size_t)NODES_PAD * 4;            // 400384 B each
    const size_t sDt   = (size_t)NODES_PAD * 4;
    const size_t sWall = (size_t)32 * 20 * 1024;           // 655360 B
    const size_t sXs   = (size_t)GROUPS_PAD * 12 * 1024;   // 76.9 MB
    const size_t sXd   = (size_t)GROUPS_PAD * 8 * 1024;    // 51.3 MB
    const size_t sHm   = (size_t)GROUPS_PAD * 4 * 1024;    // 25.6 MB
    const size_t oIdxS = 0, oIdxD = oIdxS + sIdx, oDtS = oIdxD + sIdx, oDtD = oDtS + sDt;
    const size_t oWall = oDtD + sDt, oXs = oWall + sWall, oXd = oXs + sXs, oHm = oXd + sXd;
    const size_t need  = oHm + sHm;                        // ~156 MB

    if (ws_size >= need) {
        int* idx_s = (int*)((char*)d_ws + oIdxS);
        int* idx_d = (int*)((char*)d_ws + oIdxD);
        float* dt_s = (float*)((char*)d_ws + oDtS);
        float* dt_d = (float*)((char*)d_ws + oDtD);
        unsigned short* Wsw = (unsigned short*)((char*)d_ws + oWall);
        unsigned short* Xs  = (unsigned short*)((char*)d_ws + oXs);
        unsigned short* Xd  = (unsigned short*)((char*)d_ws + oXd);
        unsigned short* Hm  = (unsigned short*)((char*)d_ws + oHm);

        hipMemsetAsync(d_ws, 0xFF, 2 * sIdx, stream);      // idx arrays = -1
        scatter_last_kernel<<<(N_EDGES_C + 255) / 256, 256, 0, stream>>>(src, dst, idx_s, idx_d);
        build_wallsw_kernel<<<160, 256, 0, stream>>>(W_ih, W_hh, Wsw);
        gather_kernel<<<N_NODES_C / 16, 256, 0, stream>>>(
            memory, last_update, edge_times, edge_feat, src, dst,
            idx_s, idx_d, dt_s, dt_d, Xs, Xd, out_mem, out_lu);
        gemm_pass_kernel<0><<<GROUPS_PAD / 8, 512, 0, stream>>>(
            memory, Wsw, b_ih, b_hh, Xs, Xd, Hm, dt_s, idx_s, out_mem);
        gemm_pass_kernel<1><<<GROUPS_PAD / 8, 512, 0, stream>>>(
            memory, Wsw, b_ih, b_hh, Xs, Xd, Hm, dt_d, idx_d, out_mem);
    } else {
        // R2 fused fallback (needs ~1.5 MB ws)
        int* idx_s = (int*)d_ws;
        int* idx_d = idx_s + N_NODES_C;
        unsigned short* Wall = (unsigned short*)((char*)d_ws + 2 * N_NODES_C * sizeof(int));
        hipMemsetAsync(d_ws, 0xFF, 2 * N_NODES_C * sizeof(int), stream);
        scatter_last_kernel<<<(N_EDGES_C + 255) / 256, 256, 0, stream>>>(src, dst, idx_s, idx_d);
        build_wall_kernel<<<(WROWS * NXF + 255) / 256, 256, 0, stream>>>(W_ih, W_hh, Wall);
        gru_mfma_kernel<0><<<N_NODES_C / NODES_PB, 256, 0, stream>>>(
            memory, last_update, Wall, b_ih, b_hh, edge_times, edge_feat,
            src, dst, idx_s, out_mem, out_lu);
        gru_mfma_kernel<1><<<N_NODES_C / NODES_PB, 256, 0, stream>>>(
            memory, last_update, Wall, b_ih, b_hh, edge_times, edge_feat,
            src, dst, idx_d, out_mem, out_lu);
    }
}